// Round 17
// baseline (12750.138 us; speedup 1.0000x reference)
//
#include <hip/hip_runtime.h>
#include <math.h>

#define NL 24
#define NB 64
#define TPB 512
#define QROWS 765
// ---- ws layout (float units) ----
#define RING_F  3133440                     // [64][765][64]
#define CVP_OFF RING_F                      // conv pack: [24][8][512] f4
#define RP_OFF  (CVP_OFF + 24*8*512*4)      // res  pack: [24][2][512] f4
#define SP_OFF  (RP_OFF  + 24*2*512*4)      // skip pack: [24][8][512] f4
#define PH_OFF  (SP_OFF  + 24*8*512*4)      // head pack: [16][32][64] f4

typedef float vf4 __attribute__((ext_vector_type(4)));

struct WBc { float4 v[8]; };   // conv frag (32 VGPR) — double-buffered
struct WBr { float4 v[2]; };   // res frag (8 VGPR) — single, per-phase
struct SWB { float4 v[8]; };   // skip frag for head GEMM — double-buffered

__device__ __forceinline__ float hadd4(float4 v) { return (v.x + v.y) + (v.z + v.w); }
__device__ __forceinline__ void fma4(float4& a, float4 x, float4 w) {
    a.x = fmaf(x.x, w.x, a.x); a.y = fmaf(x.y, w.y, a.y);
    a.z = fmaf(x.z, w.z, a.z); a.w = fmaf(x.w, w.w, a.w);
}
// barrier WITHOUT vmcnt drain (register weight prefetches stay in flight)
__device__ __forceinline__ void bar() {
    asm volatile("s_waitcnt lgkmcnt(0)" ::: "memory");
    __builtin_amdgcn_s_barrier();
    asm volatile("" ::: "memory");
}
__device__ __forceinline__ void pf_c(WBc& b, const float4* __restrict__ cvp, int i, int tid) {
    const float4* p = cvp + (size_t)i * (8 * 512) + tid;
#pragma unroll
    for (int j = 0; j < 8; ++j) b.v[j] = p[j * 512];
}
__device__ __forceinline__ void pf_r(WBr& b, const float4* __restrict__ rp, int i, int tid) {
    const float4* p = rp + (size_t)i * (2 * 512) + tid;
#pragma unroll
    for (int j = 0; j < 2; ++j) b.v[j] = p[j * 512];
}
__device__ __forceinline__ void pf_s(SWB& b, const float4* __restrict__ sp, int i, int tid) {
    const float4* p = sp + (size_t)i * (8 * 512) + tid;
#pragma unroll
    for (int j = 0; j < 8; ++j) b.v[j] = p[j * 512];
}

// ---------------- repack: lane-major packs ----------------
__global__ void repack(const float* __restrict__ conv_k, const float* __restrict__ res_w,
                       const float* __restrict__ skip_w, const float* __restrict__ out0_w,
                       const float* __restrict__ out1_w, float* __restrict__ ws) {
    const int bb = blockIdx.x, tid = threadIdx.x;
    float4* CVP = (float4*)(ws + CVP_OFF);
    float4* RP  = (float4*)(ws + RP_OFF);
    float4* SP  = (float4*)(ws + SP_OFF);
    float4* PH  = (float4*)(ws + PH_OFF);
    if (bb < NL) {
        const int i = bb, w = tid >> 6, l = tid & 63;
        const int c  = w * 8 + (l & 7);
        const int kb = (l >> 3) * 16;          // K-chunk over [xlast(64); xcur(64)]
        float4* dst = CVP + (size_t)i * (8 * 512) + tid;
#pragma unroll
        for (int half = 0; half < 2; ++half) {
            const int cc = c + half * 64;
#pragma unroll
            for (int j = 0; j < 4; ++j) {
                float4 v; const int k0 = kb + j * 4;
                v.x = conv_k[(((size_t)i * 2 + ((k0+0) >> 6)) * 64 + ((k0+0) & 63)) * 128 + cc];
                v.y = conv_k[(((size_t)i * 2 + ((k0+1) >> 6)) * 64 + ((k0+1) & 63)) * 128 + cc];
                v.z = conv_k[(((size_t)i * 2 + ((k0+2) >> 6)) * 64 + ((k0+2) & 63)) * 128 + cc];
                v.w = conv_k[(((size_t)i * 2 + ((k0+3) >> 6)) * 64 + ((k0+3) & 63)) * 128 + cc];
                dst[(half * 4 + j) * 512] = v;
            }
        }
        const int kr = (l >> 3) * 8;
        float4* rdst = RP + (size_t)i * (2 * 512) + tid;
#pragma unroll
        for (int j = 0; j < 2; ++j) {
            float4 v; const int k0 = kr + j * 4;
            v.x = res_w[((size_t)i * 64 + k0 + 0) * 64 + c];
            v.y = res_w[((size_t)i * 64 + k0 + 1) * 64 + c];
            v.z = res_w[((size_t)i * 64 + k0 + 2) * 64 + c];
            v.w = res_w[((size_t)i * 64 + k0 + 3) * 64 + c];
            rdst[j * 512] = v;
        }
        const int s  = tid >> 1;               // skip col (0..255)
        const int kh = (tid & 1) * 32;         // skip K-half
        float4* sdst = SP + (size_t)i * (8 * 512) + tid;
#pragma unroll
        for (int j = 0; j < 8; ++j) {
            float4 v; const int k0 = kh + j * 4;
            v.x = skip_w[((size_t)i * 64 + k0 + 0) * 256 + s];
            v.y = skip_w[((size_t)i * 64 + k0 + 1) * 256 + s];
            v.z = skip_w[((size_t)i * 64 + k0 + 2) * 256 + s];
            v.w = skip_w[((size_t)i * 64 + k0 + 3) * 256 + s];
            sdst[j * 512] = v;
        }
    } else {
        if (tid >= 64) return;
        const int hb = bb - NL;                // 0..15: [which][wave]
        const int which = hb >> 3, w = hb & 7, l = tid;
        const float* W = which ? out1_w : out0_w;
        float4* dst = PH + (size_t)hb * (32 * 64) + l;
        const int c  = w * 32 + (l & 31);
        const int kb = (l >> 5) * 128;
        for (int j = 0; j < 32; ++j) {
            float4 v; const int k0 = kb + j * 4;
            v.x = W[(size_t)(k0 + 0) * 256 + c];
            v.y = W[(size_t)(k0 + 1) * 256 + c];
            v.z = W[(size_t)(k0 + 2) * 256 + c];
            v.w = W[(size_t)(k0 + 3) * 256 + c];
            dst[j * 64] = v;
        }
    }
}

// ---------------- main generator: one block per batch, 8 waves, skip-at-head ----------------
__global__ __launch_bounds__(TPB, 1)
void wavenet_gen(const int* __restrict__ seed,
                 const float* __restrict__ embed,
                 const float* __restrict__ conv_b,
                 const float* __restrict__ res_b,
                 const float* __restrict__ skip_b,
                 const float* __restrict__ out0_b,
                 const float* __restrict__ out1_b,
                 const int* __restrict__ Tptr,
                 float* __restrict__ out,
                 float* __restrict__ ring,
                 const float4* __restrict__ cvp,
                 const float4* __restrict__ rp,
                 const float4* __restrict__ sp,
                 const float4* __restrict__ php)
{
    const int b   = blockIdx.x;
    const int tid = threadIdx.x;
    const int w   = tid >> 6;
    const int l   = tid & 63;
    const int T   = *Tptr;

    __shared__ __align__(16) float x2[128];            // [0:64) x_last, [64:128) x_cur
    __shared__ __align__(16) float gAll[NL * 64];      // all gate vectors of this step
    __shared__ __align__(16) float skl[256];
    __shared__ __align__(16) float h0l[256];
    __shared__ __align__(16) float ebt[256 * 64];      // embed table
    __shared__ __align__(16) float cb[NL * 128];
    __shared__ __align__(16) float rbS[NL * 64];
    __shared__ __align__(16) float o0b[256], o1b[256], sbt[256];
    __shared__ float wmaxv[8];
    __shared__ int   wmaxi[8];

    float* q = ring + (size_t)b * (QROWS * 64);

    // ---- init: zero queue ring (NT); stage LDS ----
    {
        vf4* q4 = (vf4*)q;
        const vf4 z = (vf4){0.f, 0.f, 0.f, 0.f};
        for (int idx = tid; idx < QROWS * 64 / 4; idx += TPB)
            __builtin_nontemporal_store(z, &q4[idx]);
        const float4* s4; float4* d4;
        s4 = (const float4*)embed;  d4 = (float4*)ebt;
        for (int idx = tid; idx < 256 * 64 / 4; idx += TPB) d4[idx] = s4[idx];
        s4 = (const float4*)conv_b; d4 = (float4*)cb;
        for (int idx = tid; idx < NL * 128 / 4; idx += TPB) d4[idx] = s4[idx];
        s4 = (const float4*)res_b;  d4 = (float4*)rbS;
        for (int idx = tid; idx < NL * 64 / 4; idx += TPB) d4[idx] = s4[idx];
        s4 = (const float4*)out0_b; d4 = (float4*)o0b;
        for (int idx = tid; idx < 64; idx += TPB) d4[idx] = s4[idx];
        s4 = (const float4*)out1_b; d4 = (float4*)o1b;
        for (int idx = tid; idx < 64; idx += TPB) d4[idx] = s4[idx];
        if (tid < 256) {                     // sbt = sum_i skip_b[i]
            float acc = 0.f;
            for (int i = 0; i < NL; ++i) acc += skip_b[i * 256 + tid];
            sbt[tid] = acc;
        }
    }
    __syncthreads();
    if (tid < 64) {
        x2[tid] = 0.f;                                   // x_last(layer0, t=0) = 0
        const int smp = seed[b];
        x2[64 + tid] = ebt[smp * 64 + tid];              // x_cur = embed[seed]
    }
    __syncthreads();

    WBc CVa, CVb;     // conv fragments, double-buffered
    WBr RS;           // res fragment, single-buffered (issued top-of-alpha, used in beta)
    pf_c(CVa, cvp, 0, tid);

    float* out_pred = out + (size_t)b * T;
    float* out_log  = out + (size_t)NB * T + (size_t)b * T * 256;

    const int c   = w * 8 + (l & 7);       // conv/res column
    const int kb  = (l >> 3) * 16;         // conv K-chunk
    const int kr  = (l >> 3) * 8;          // res K-chunk
    const int sc  = tid >> 1;              // skip col (head GEMM)
    const int kh  = (tid & 1) * 32;        // skip K-half
    const int c2  = w * 32 + (l & 31);     // head column
    const int kb2 = (l >> 5) * 128;        // head K-half

    for (int t = 0; t < T; ++t) {

        auto layer = [&](WBc& cur, WBc& nxt, const int i) {
            const int inx = (i + 1 < NL) ? (i + 1) : 0;
            // ---------------- phase alpha ----------------
            // RS (used in beta) first; conv-next second: beta's counted vmcnt
            // leaves the conv prefetch in flight.
            pf_r(RS, rp, i, tid);
            if (inx) pf_c(nxt, cvp, inx, tid);    // layer-0 prefetch moved to head C
            float xlnext = 0.f;
            if (w == 7) {                         // early ring read (NT: keep out of L2)
                const int d2 = 1 << (inx & 7);
                const int row2 = 255 * (inx >> 3) + (d2 - 1) + (t & (d2 - 1));
                xlnext = __builtin_nontemporal_load(&q[(size_t)row2 * 64 + l]);
            }
            if (w == 6) {                         // queue push of this layer's input (NT)
                const int d = 1 << (i & 7);
                const int row = 255 * (i >> 3) + (d - 1) + (t & (d - 1));
                __builtin_nontemporal_store(x2[64 + l], &q[(size_t)row * 64 + l]);
            }
            // conv partials (own 16-K chunk, cols c and c+64)
            float4 xk0 = *(const float4*)&x2[kb];
            float4 xk1 = *(const float4*)&x2[kb + 4];
            float4 xk2 = *(const float4*)&x2[kb + 8];
            float4 xk3 = *(const float4*)&x2[kb + 12];
            float4 aA = make_float4(0.f, 0.f, 0.f, 0.f);
            float4 aB = make_float4(0.f, 0.f, 0.f, 0.f);
            fma4(aA, xk0, cur.v[0]); fma4(aA, xk1, cur.v[1]);
            fma4(aA, xk2, cur.v[2]); fma4(aA, xk3, cur.v[3]);
            fma4(aB, xk0, cur.v[4]); fma4(aB, xk1, cur.v[5]);
            fma4(aB, xk2, cur.v[6]); fma4(aB, xk3, cur.v[7]);
            float hA = hadd4(aA), hB = hadd4(aB);
            hA += __shfl_xor(hA, 8);  hB += __shfl_xor(hB, 8);
            hA += __shfl_xor(hA, 16); hB += __shfl_xor(hB, 16);
            hA += __shfl_xor(hA, 32); hB += __shfl_xor(hB, 32);
            hA += cb[i * 128 + c];
            hB += cb[i * 128 + 64 + c];
            const float g = tanhf(hA) * (1.f / (1.f + expf(-hB)));
            if (l < 8) gAll[i * 64 + w * 8 + l] = g;   // c == w*8+l here
            bar();
            // ---------------- phase beta (res only; skip deferred to head) ----------------
            float4 gr0 = *(const float4*)&gAll[i * 64 + kr];
            float4 gr1 = *(const float4*)&gAll[i * 64 + kr + 4];
            float4 ra = make_float4(0.f, 0.f, 0.f, 0.f);
            fma4(ra, gr0, RS.v[0]); fma4(ra, gr1, RS.v[1]);
            float racc = hadd4(ra);
            racc += __shfl_xor(racc, 8);
            racc += __shfl_xor(racc, 16);
            racc += __shfl_xor(racc, 32);
            const float xnew = x2[64 + c] + racc + rbS[i * 64 + c];
            if (l < 8) x2[64 + w * 8 + l] = xnew;   // residual out -> x_cur
            if (w == 7) x2[l] = xlnext;             // next layer's x_last
            bar();
        };

#pragma unroll 1
        for (int ii = 0; ii < NL; ii += 2) {
            layer(CVa, CVb, ii);
            layer(CVb, CVa, ii + 1);
        }

        // ---------------- head A: skip GEMM over all 24 layers (barrier-free) ----------------
        {
            SWB sA, sB;
            pf_s(sA, sp, 0, tid);
            float sk = 0.f;
#pragma unroll
            for (int ii = 0; ii < NL; ii += 2) {
                pf_s(sB, sp, ii + 1, tid);
                {
                    const float* gi = &gAll[ii * 64 + kh];
                    float4 acc = make_float4(0.f, 0.f, 0.f, 0.f);
#pragma unroll
                    for (int j = 0; j < 8; ++j)
                        fma4(acc, *(const float4*)&gi[j * 4], sA.v[j]);
                    sk += hadd4(acc);
                }
                if (ii + 2 < NL) pf_s(sA, sp, ii + 2, tid);
                {
                    const float* gi = &gAll[(ii + 1) * 64 + kh];
                    float4 acc = make_float4(0.f, 0.f, 0.f, 0.f);
#pragma unroll
                    for (int j = 0; j < 8; ++j)
                        fma4(acc, *(const float4*)&gi[j * 4], sB.v[j]);
                    sk += hadd4(acc);
                }
            }
            sk += __shfl_xor(sk, 1);               // combine the two K-halves of col sc
            if ((tid & 1) == 0) skl[sc] = sk + sbt[sc];
        }
        bar();
        // ---------------- head B: GEMV1 h0 = relu(skl @ out0_w + b0) ----------------
        {
            const float4* hp = php + ((size_t)w * 32) * 64 + l;
            float4 ha = make_float4(0.f, 0.f, 0.f, 0.f);
#pragma unroll 8
            for (int cc = 0; cc < 32; ++cc) {
                float4 wv = hp[cc * 64];
                float4 sv = *(const float4*)&skl[kb2 + cc * 4];
                fma4(ha, sv, wv);
            }
            float hs = hadd4(ha);
            hs += __shfl_xor(hs, 32);
            const float h0 = fmaxf(hs + o0b[c2], 0.f);
            if (l < 32) h0l[c2] = h0;
        }
        bar();
        // ---------------- head C: GEMV2 + wave argmax (also prefetch layer-0 conv) ----------------
        pf_c(CVa, cvp, 0, tid);                    // next step's layer-0 weights
        float logit;
        {
            const float4* hp = php + ((size_t)(8 + w) * 32) * 64 + l;
            float4 la = make_float4(0.f, 0.f, 0.f, 0.f);
#pragma unroll 8
            for (int cc = 0; cc < 32; ++cc) {
                float4 wv = hp[cc * 64];
                float4 hv = *(const float4*)&h0l[kb2 + cc * 4];
                fma4(la, hv, wv);
            }
            float ls = hadd4(la);
            ls += __shfl_xor(ls, 32);
            logit = ls + o1b[c2];
            if (l < 32)
                __builtin_nontemporal_store(logit, &out_log[(size_t)t * 256 + c2]);
        }
        {
            float bv = logit; int bi = c2;
#pragma unroll
            for (int off = 1; off <= 16; off <<= 1) {
                const float ov = __shfl_xor(bv, off);
                const int   oi = __shfl_xor(bi, off);
                if (ov > bv || (ov == bv && oi < bi)) { bv = ov; bi = oi; }
            }
            if (l == 0) { wmaxv[w] = bv; wmaxi[w] = bi; }
        }
        bar();
        // ---------------- head D: final argmax, next-step state, mu-law ----------------
        {
            float fv = wmaxv[0]; int fi = wmaxi[0];
#pragma unroll
            for (int ww = 1; ww < 8; ++ww) {
                const float vv = wmaxv[ww]; const int vi = wmaxi[ww];
                if (vv > fv || (vv == fv && vi < fi)) { fv = vv; fi = vi; }
            }
            if (tid < 64) x2[64 + tid] = ebt[fi * 64 + tid];   // x_cur of next step
            if (tid == 0) {
                const float mw = (float)fi * (2.0f / 255.0f) - 1.0f;
                const float a  = fabsf(mw);
                const float p  = (exp2f(8.0f * a) - 1.0f) * (1.0f / 255.0f);
                __builtin_nontemporal_store((mw < 0.f) ? -p : p, &out_pred[t]);
            }
        }
        bar();
    }
}

extern "C" void kernel_launch(void* const* d_in, const int* in_sizes, int n_in,
                              void* d_out, int out_size, void* d_ws, size_t ws_size,
                              hipStream_t stream) {
    const int*   seed   = (const int*)  d_in[0];
    const float* embed  = (const float*)d_in[1];
    const float* conv_k = (const float*)d_in[2];
    const float* conv_b = (const float*)d_in[3];
    const float* res_w  = (const float*)d_in[4];
    const float* res_b  = (const float*)d_in[5];
    const float* skip_w = (const float*)d_in[6];
    const float* skip_b = (const float*)d_in[7];
    const float* out0_w = (const float*)d_in[8];
    const float* out0_b = (const float*)d_in[9];
    const float* out1_w = (const float*)d_in[10];
    const float* out1_b = (const float*)d_in[11];
    const int*   Tptr   = (const int*)  d_in[12];

    float* ws = (float*)d_ws;
    float* ring = ws;
    const float4* cvp = (const float4*)(ws + CVP_OFF);
    const float4* rp  = (const float4*)(ws + RP_OFF);
    const float4* sp  = (const float4*)(ws + SP_OFF);
    const float4* php = (const float4*)(ws + PH_OFF);

    repack<<<dim3(NL + 16), dim3(TPB), 0, stream>>>(
        conv_k, res_w, skip_w, out0_w, out1_w, ws);

    wavenet_gen<<<dim3(NB), dim3(TPB), 0, stream>>>(
        seed, embed, conv_b, res_b, skip_b, out0_b, out1_b, Tptr,
        (float*)d_out, ring, cvp, rp, sp, php);
}